// Round 6
// baseline (751.962 us; speedup 1.0000x reference)
//
#include <hip/hip_runtime.h>

typedef _Float16 f16;
typedef _Float16 f16x8 __attribute__((ext_vector_type(8)));
typedef _Float16 f16x4 __attribute__((ext_vector_type(4)));
typedef float    f32x16 __attribute__((ext_vector_type(16)));

#define GLD16(g, l)                                                            \
  __builtin_amdgcn_global_load_lds(                                            \
      (const __attribute__((address_space(1))) void*)(g),                      \
      (__attribute__((address_space(3))) void*)(l), 16, 0, 0)

static constexpr int S = 4096, H = 2048, B = 2;

// ------------------------------------------- single fused cast: hs | Wq|Wk|Wv
__global__ __launch_bounds__(256) void cast_all(
    const float* __restrict__ hs, const float* __restrict__ w0,
    const float* __restrict__ w1, const float* __restrict__ w2,
    f16* __restrict__ hs_h, f16* __restrict__ w_h) {
  const int hsN4 = B * S * H / 4;  // float4 groups in hs
  const int wN4  = H * H / 4;     // float4 groups per weight
  int i = blockIdx.x * 256 + threadIdx.x;
  float4 f;
  if (i < hsN4) {
    f = reinterpret_cast<const float4*>(hs)[i];
    f16x4 h = {(f16)f.x, (f16)f.y, (f16)f.z, (f16)f.w};
    reinterpret_cast<f16x4*>(hs_h)[i] = h;
  } else {
    int j = i - hsN4;
    int seg = j / wN4, off = j - seg * wN4;
    const float* src = seg == 0 ? w0 : (seg == 1 ? w1 : w2);
    f = reinterpret_cast<const float4*>(src)[off];
    f16x4 h = {(f16)f.x, (f16)f.y, (f16)f.z, (f16)f.w};
    reinterpret_cast<f16x4*>(w_h)[j] = h;
  }
}

// ---------------------------------------------------------------- TN GEMM
// C[m,n] = sum_k A[m,k]*B[n,k], 128x128 tile, BK=64, xor-swizzled LDS,
// 32x32x16 MFMA (2x2 frags / wave). 2D grid, x = N-tile fastest (XCD-pinned B).
// MODE 0: fused QKV.  n<2048 -> Q(+bq) f16; <4096 -> K(+bk); else Vt[b][h][s](+bv)
// MODE 2: scores, batched. f16 out = v*scale + mask[b][n]
// MODE 3: PV, batched. f32 out.
template <int MODE>
__global__ __launch_bounds__(256) void gemm_tn(
    const f16* __restrict__ A, const f16* __restrict__ Bm,
    void* __restrict__ C0, void* __restrict__ C1, void* __restrict__ C2,
    const float* __restrict__ x0, const float* __restrict__ x1,
    const float* __restrict__ x2, float scale, int K, int lda, int ldb) {
  __shared__ __attribute__((aligned(16))) char smem[32768];
  f16* sA = (f16*)smem;
  f16* sB = (f16*)(smem + 16384);

  const int tileM = blockIdx.y * 128;
  const int tileN = blockIdx.x * 128;

  const int tid  = threadIdx.x;
  const int wave = tid >> 6, lane = tid & 63;
  const int wm = (wave >> 1) * 64, wn = (wave & 1) * 64;
  const int l31 = lane & 31, khalf = lane >> 5;

  f32x16 acc[2][2] = {};

  // batch-aware operand row bases (tiles never straddle batches: S%128==0)
  size_t rowA = tileM, rowB = tileN;
  if (MODE == 2) rowB = (size_t)(tileM >> 12) * S + tileN;  // Kh row = b*S + k
  if (MODE == 3) rowB = (size_t)(tileM >> 12) * H + tileN;  // Vt row = b*H + h
  const f16* gA = A + rowA * lda;
  const f16* gB = Bm + rowB * ldb;

  // staging: 128 rows x 8 chunks(16B); chunk stored at slot (srcchunk ^ (row&7))
  size_t aoff[4], boff[4];
  int ldsoff[4];
#pragma unroll
  for (int j = 0; j < 4; ++j) {
    int id = j * 256 + tid;
    int r = id >> 3, cs = (id & 7) ^ (r & 7);
    aoff[j] = (size_t)r * lda + cs * 8;
    boff[j] = (size_t)r * ldb + cs * 8;
    ldsoff[j] = id * 8;
  }

  for (int k0 = 0; k0 < K; k0 += 64) {
#pragma unroll
    for (int j = 0; j < 4; ++j) {
      GLD16(gA + aoff[j] + k0, &sA[ldsoff[j]]);
      GLD16(gB + boff[j] + k0, &sB[ldsoff[j]]);
    }
    __syncthreads();
#pragma unroll
    for (int c = 0; c < 4; ++c) {  // 4 K16-chunks per BK=64
      f16x8 af[2], bf[2];
      const int pos = ((c * 2 + khalf) ^ (lane & 7)) * 8;  // xor-unswizzle
#pragma unroll
      for (int x = 0; x < 2; ++x)
        af[x] = *reinterpret_cast<const f16x8*>(&sA[(wm + x * 32 + l31) * 64 + pos]);
#pragma unroll
      for (int y = 0; y < 2; ++y)
        bf[y] = *reinterpret_cast<const f16x8*>(&sB[(wn + y * 32 + l31) * 64 + pos]);
#pragma unroll
      for (int x = 0; x < 2; ++x)
#pragma unroll
        for (int y = 0; y < 2; ++y)
          acc[x][y] = __builtin_amdgcn_mfma_f32_32x32x16_f16(af[x], bf[y], acc[x][y], 0, 0, 0);
    }
    __syncthreads();
  }

  // ---- V epilogue (MODE 0, seg==2): LDS transpose, two 64-col passes
  if (MODE == 0 && (tileN >> 11) == 2) {
    const int nn0 = tileN - 2 * H;
    const int b = tileM >> 12, s0 = tileM & (S - 1);
    f16* sT = (f16*)smem;  // [col 0..63][row 0..127], stride 136 (17408 B)
#pragma unroll
    for (int p = 0; p < 2; ++p) {
      if ((wn >> 6) == p) {
#pragma unroll
        for (int x = 0; x < 2; ++x)
#pragma unroll
          for (int y = 0; y < 2; ++y) {
            int scol = y * 32 + l31;
            float bias = x2[nn0 + p * 64 + scol];
#pragma unroll
            for (int g = 0; g < 4; ++g) {
              int row = wm + x * 32 + g * 8 + khalf * 4;
              f16x4 h4 = {(f16)(acc[x][y][g * 4 + 0] + bias),
                          (f16)(acc[x][y][g * 4 + 1] + bias),
                          (f16)(acc[x][y][g * 4 + 2] + bias),
                          (f16)(acc[x][y][g * 4 + 3] + bias)};
              *reinterpret_cast<f16x4*>(&sT[scol * 136 + row]) = h4;
            }
          }
      }
      __syncthreads();
      {
        int c = tid >> 2, hh = tid & 3;
        const f16* src = &sT[c * 136 + hh * 32];
        f16* dst = (f16*)C2 + (size_t)b * H * S + (size_t)(nn0 + p * 64 + c) * S +
                   s0 + hh * 32;
#pragma unroll
        for (int j = 0; j < 4; ++j)
          reinterpret_cast<f16x8*>(dst)[j] = reinterpret_cast<const f16x8*>(src)[j];
      }
      __syncthreads();
    }
    return;
  }

#pragma unroll
  for (int x = 0; x < 2; ++x)
#pragma unroll
    for (int y = 0; y < 2; ++y)
#pragma unroll
      for (int r = 0; r < 16; ++r) {
        int m = tileM + wm + x * 32 + (r & 3) + 8 * (r >> 2) + 4 * khalf;
        int n = tileN + wn + y * 32 + l31;
        float v = acc[x][y][r];
        if (MODE == 0) {
          int seg = n >> 11, nn = n & 2047;  // seg 0/1 only (V handled above)
          if (seg == 0) {
            ((f16*)C0)[(size_t)m * H + nn] = (f16)(v + x0[nn]);
          } else {
            ((f16*)C1)[(size_t)m * H + nn] = (f16)(v + x1[nn]);
          }
        } else if (MODE == 2) {
          int b = m >> 12;
          ((f16*)C0)[(size_t)m * S + n] = (f16)(v * scale + x0[(size_t)b * S + n]);
        } else {
          ((float*)C0)[(size_t)m * H + n] = v;
        }
      }
}

// ------------------------------------------------- softmax over 4096 f16, in place
__global__ __launch_bounds__(256) void softmax_f16(f16* __restrict__ sc) {
  const int tid = threadIdx.x;
  f16* rp = sc + (size_t)blockIdx.x * S;
  f16x8 h[2];
#pragma unroll
  for (int j = 0; j < 2; ++j) h[j] = reinterpret_cast<f16x8*>(rp)[tid + j * 256];

  float v[16];
#pragma unroll
  for (int j = 0; j < 2; ++j)
#pragma unroll
    for (int e = 0; e < 8; ++e) v[j * 8 + e] = (float)h[j][e];

  float m = -1e30f;
#pragma unroll
  for (int e = 0; e < 16; ++e) m = fmaxf(m, v[e]);
#pragma unroll
  for (int off = 32; off; off >>= 1) m = fmaxf(m, __shfl_xor(m, off));

  __shared__ float red[8];
  int wave = tid >> 6, lane = tid & 63;
  if (lane == 0) red[wave] = m;
  __syncthreads();
  m = fmaxf(fmaxf(red[0], red[1]), fmaxf(red[2], red[3]));

  float s = 0.f;
#pragma unroll
  for (int e = 0; e < 16; ++e) { v[e] = __expf(v[e] - m); s += v[e]; }
#pragma unroll
  for (int off = 32; off; off >>= 1) s += __shfl_xor(s, off);
  if (lane == 0) red[4 + wave] = s;
  __syncthreads();
  s = red[4] + red[5] + red[6] + red[7];
  float inv = 1.0f / s;

#pragma unroll
  for (int j = 0; j < 2; ++j) {
#pragma unroll
    for (int e = 0; e < 8; ++e) h[j][e] = (f16)(v[j * 8 + e] * inv);
    reinterpret_cast<f16x8*>(rp)[tid + j * 256] = h[j];
  }
}

// ---------------------------------------------------------------- launch
extern "C" void kernel_launch(void* const* d_in, const int* in_sizes, int n_in,
                              void* d_out, int out_size, void* d_ws, size_t ws_size,
                              hipStream_t stream) {
  const float* hs   = (const float*)d_in[0];
  const float* mask = (const float*)d_in[1];
  const float* Wq   = (const float*)d_in[2];
  const float* bq   = (const float*)d_in[3];
  const float* Wk   = (const float*)d_in[4];
  const float* bk   = (const float*)d_in[5];
  const float* Wv   = (const float*)d_in[6];
  const float* bv   = (const float*)d_in[7];
  float* out = (float*)d_out;

  // workspace layout (~226 MB)
  f16* hs_h = (f16*)d_ws;                        // B*S*H
  f16* w_h  = hs_h + (size_t)B * S * H;          // 3*H*H concat
  f16* Qh   = w_h + (size_t)3 * H * H;           // B*S*H
  f16* Kh   = Qh + (size_t)B * S * H;            // B*S*H
  f16* Vt   = Kh + (size_t)B * S * H;            // B*H*S (transposed)
  f16* Sc   = Vt + (size_t)B * S * H;            // B*S*S f16

  const int castN = B * S * H / 4 + 3 * H * H / 4;
  cast_all<<<(castN + 255) / 256, 256, 0, stream>>>(hs, Wq, Wk, Wv, hs_h, w_h);

  dim3 blk(256);
  const float sscale = 0.088388347648318447f;  // 1/sqrt(HEAD_SIZE=128)

  // fused QKV: M=8192, N=6144, K=2048. grid (48,64), x fastest
  gemm_tn<0><<<dim3(48, 64), blk, 0, stream>>>(
      hs_h, w_h, Qh, Kh, Vt, bq, bk, bv, 1.f, H, H, H);

  // scores both batches: M=8192, N=4096, K=2048. grid (32,64)
  gemm_tn<2><<<dim3(32, 64), blk, 0, stream>>>(
      Qh, Kh, Sc, nullptr, nullptr, mask, nullptr, nullptr, sscale, H, H, H);

  softmax_f16<<<B * S, 256, 0, stream>>>(Sc);

  // PV both batches: M=8192, N=2048, K=4096. grid (16,64)
  gemm_tn<3><<<dim3(16, 64), blk, 0, stream>>>(
      Sc, Vt, out, nullptr, nullptr, nullptr, nullptr, nullptr, 1.f, S, S, S);
}

// Round 7
// 686.584 us; speedup vs baseline: 1.0952x; 1.0952x over previous
//
#include <hip/hip_runtime.h>

typedef _Float16 f16;
typedef _Float16 f16x8 __attribute__((ext_vector_type(8)));
typedef _Float16 f16x4 __attribute__((ext_vector_type(4)));
typedef float    f32x16 __attribute__((ext_vector_type(16)));

#define GLD16(g, l)                                                            \
  __builtin_amdgcn_global_load_lds(                                            \
      (const __attribute__((address_space(1))) void*)(g),                      \
      (__attribute__((address_space(3))) void*)(l), 16, 0, 0)

static constexpr int S = 4096, H = 2048, B = 2;

// ------------------------------------------- single fused cast: hs | Wq|Wk|Wv
__global__ __launch_bounds__(256) void cast_all(
    const float* __restrict__ hs, const float* __restrict__ w0,
    const float* __restrict__ w1, const float* __restrict__ w2,
    f16* __restrict__ hs_h, f16* __restrict__ w_h) {
  const int hsN4 = B * S * H / 4;  // float4 groups in hs
  const int wN4  = H * H / 4;     // float4 groups per weight
  int i = blockIdx.x * 256 + threadIdx.x;
  float4 f;
  if (i < hsN4) {
    f = reinterpret_cast<const float4*>(hs)[i];
    f16x4 h = {(f16)f.x, (f16)f.y, (f16)f.z, (f16)f.w};
    reinterpret_cast<f16x4*>(hs_h)[i] = h;
  } else {
    int j = i - hsN4;
    int seg = j / wN4, off = j - seg * wN4;
    const float* src = seg == 0 ? w0 : (seg == 1 ? w1 : w2);
    f = reinterpret_cast<const float4*>(src)[off];
    f16x4 h = {(f16)f.x, (f16)f.y, (f16)f.z, (f16)f.w};
    reinterpret_cast<f16x4*>(w_h)[j] = h;
  }
}

// ---------------------------------------------------------------- TN GEMM
// C[m,n] = sum_k A[m,k]*B[n,k], 128x128 tile, BK=64, 32x32x16 MFMA (2x2/wave).
// LDS swizzle: chunk (row,kc) stored at line-slot kc ^ (row&7) ^ ((row&16)>>2)
// -> conflict-free for 32-row fragment reads (phase {l,l+16,l+32,l+48} gets
// slots {s,s^4,s^1,s^5}; each 16-lane group covers 8 slots 2x = free).
// 2D grid, x = N-tile fastest (XCD-pinned B panels).
// MODE 0: fused QKV.  n<2048 -> Q(+bq) f16; <4096 -> K(+bk); else Vt[b][h][s](+bv)
// MODE 2: scores, batched. f16 out = v*scale + mask[b][n]
// MODE 3: PV, batched. f32 out.
template <int MODE>
__global__ __launch_bounds__(256) void gemm_tn(
    const f16* __restrict__ A, const f16* __restrict__ Bm,
    void* __restrict__ C0, void* __restrict__ C1, void* __restrict__ C2,
    const float* __restrict__ x0, const float* __restrict__ x1,
    const float* __restrict__ x2, float scale, int K, int lda, int ldb) {
  __shared__ __attribute__((aligned(16))) char smem[32768];
  f16* sA = (f16*)smem;
  f16* sB = (f16*)(smem + 16384);

  const int tileM = blockIdx.y * 128;
  const int tileN = blockIdx.x * 128;

  const int tid  = threadIdx.x;
  const int wave = tid >> 6, lane = tid & 63;
  const int wm = (wave >> 1) * 64, wn = (wave & 1) * 64;
  const int l31 = lane & 31, khalf = lane >> 5;

  f32x16 acc[2][2] = {};

  // batch-aware operand row bases (tiles never straddle batches: S%128==0)
  size_t rowA = tileM, rowB = tileN;
  if (MODE == 2) rowB = (size_t)(tileM >> 12) * S + tileN;  // Kh row = b*S + k
  if (MODE == 3) rowB = (size_t)(tileM >> 12) * H + tileN;  // Vt row = b*H + h
  const f16* gA = A + rowA * lda;
  const f16* gB = Bm + rowB * ldb;

  // staging: 128 rows x 8 chunks(16B); line-slot s holds source chunk
  // kc = s ^ (r&7) ^ ((r&16)>>2)   (XOR involution: read uses same formula)
  size_t aoff[4], boff[4];
  int ldsoff[4];
#pragma unroll
  for (int j = 0; j < 4; ++j) {
    int id = j * 256 + tid;
    int r = id >> 3, cs = (id & 7) ^ (r & 7) ^ ((r & 16) >> 2);
    aoff[j] = (size_t)r * lda + cs * 8;
    boff[j] = (size_t)r * ldb + cs * 8;
    ldsoff[j] = id * 8;
  }

  // fragment-read swizzle term (row&7 == l31&7, row&16 == l31&16 for all frags)
  const int rsw = (l31 & 7) ^ ((l31 & 16) >> 2);

  for (int k0 = 0; k0 < K; k0 += 64) {
#pragma unroll
    for (int j = 0; j < 4; ++j) {
      GLD16(gA + aoff[j] + k0, &sA[ldsoff[j]]);
      GLD16(gB + boff[j] + k0, &sB[ldsoff[j]]);
    }
    __syncthreads();
#pragma unroll
    for (int c = 0; c < 4; ++c) {  // 4 K16-chunks per BK=64
      f16x8 af[2], bf[2];
      const int pos = ((c * 2 + khalf) ^ rsw) * 8;  // xor-unswizzle
#pragma unroll
      for (int x = 0; x < 2; ++x)
        af[x] = *reinterpret_cast<const f16x8*>(&sA[(wm + x * 32 + l31) * 64 + pos]);
#pragma unroll
      for (int y = 0; y < 2; ++y)
        bf[y] = *reinterpret_cast<const f16x8*>(&sB[(wn + y * 32 + l31) * 64 + pos]);
#pragma unroll
      for (int x = 0; x < 2; ++x)
#pragma unroll
        for (int y = 0; y < 2; ++y)
          acc[x][y] = __builtin_amdgcn_mfma_f32_32x32x16_f16(af[x], bf[y], acc[x][y], 0, 0, 0);
    }
    __syncthreads();
  }

  // ---- V epilogue (MODE 0, seg==2): LDS transpose, two 64-col passes
  if (MODE == 0 && (tileN >> 11) == 2) {
    const int nn0 = tileN - 2 * H;
    const int b = tileM >> 12, s0 = tileM & (S - 1);
    f16* sT = (f16*)smem;  // [col 0..63][row 0..127], stride 136 (17408 B)
#pragma unroll
    for (int p = 0; p < 2; ++p) {
      if ((wn >> 6) == p) {
#pragma unroll
        for (int x = 0; x < 2; ++x)
#pragma unroll
          for (int y = 0; y < 2; ++y) {
            int scol = y * 32 + l31;
            float bias = x2[nn0 + p * 64 + scol];
#pragma unroll
            for (int g = 0; g < 4; ++g) {
              int row = wm + x * 32 + g * 8 + khalf * 4;
              f16x4 h4 = {(f16)(acc[x][y][g * 4 + 0] + bias),
                          (f16)(acc[x][y][g * 4 + 1] + bias),
                          (f16)(acc[x][y][g * 4 + 2] + bias),
                          (f16)(acc[x][y][g * 4 + 3] + bias)};
              *reinterpret_cast<f16x4*>(&sT[scol * 136 + row]) = h4;
            }
          }
      }
      __syncthreads();
      {
        int c = tid >> 2, hh = tid & 3;
        const f16* src = &sT[c * 136 + hh * 32];
        f16* dst = (f16*)C2 + (size_t)b * H * S + (size_t)(nn0 + p * 64 + c) * S +
                   s0 + hh * 32;
#pragma unroll
        for (int j = 0; j < 4; ++j)
          reinterpret_cast<f16x8*>(dst)[j] = reinterpret_cast<const f16x8*>(src)[j];
      }
      __syncthreads();
    }
    return;
  }

#pragma unroll
  for (int x = 0; x < 2; ++x)
#pragma unroll
    for (int y = 0; y < 2; ++y)
#pragma unroll
      for (int r = 0; r < 16; ++r) {
        int m = tileM + wm + x * 32 + (r & 3) + 8 * (r >> 2) + 4 * khalf;
        int n = tileN + wn + y * 32 + l31;
        float v = acc[x][y][r];
        if (MODE == 0) {
          int seg = n >> 11, nn = n & 2047;  // seg 0/1 only (V handled above)
          if (seg == 0) {
            ((f16*)C0)[(size_t)m * H + nn] = (f16)(v + x0[nn]);
          } else {
            ((f16*)C1)[(size_t)m * H + nn] = (f16)(v + x1[nn]);
          }
        } else if (MODE == 2) {
          int b = m >> 12;
          ((f16*)C0)[(size_t)m * S + n] = (f16)(v * scale + x0[(size_t)b * S + n]);
        } else {
          ((float*)C0)[(size_t)m * H + n] = v;
        }
      }
}

// ------------------------------------------------- softmax over 4096 f16, in place
__global__ __launch_bounds__(256) void softmax_f16(f16* __restrict__ sc) {
  const int tid = threadIdx.x;
  f16* rp = sc + (size_t)blockIdx.x * S;
  f16x8 h[2];
#pragma unroll
  for (int j = 0; j < 2; ++j) h[j] = reinterpret_cast<f16x8*>(rp)[tid + j * 256];

  float v[16];
#pragma unroll
  for (int j = 0; j < 2; ++j)
#pragma unroll
    for (int e = 0; e < 8; ++e) v[j * 8 + e] = (float)h[j][e];

  float m = -1e30f;
#pragma unroll
  for (int e = 0; e < 16; ++e) m = fmaxf(m, v[e]);
#pragma unroll
  for (int off = 32; off; off >>= 1) m = fmaxf(m, __shfl_xor(m, off));

  __shared__ float red[8];
  int wave = tid >> 6, lane = tid & 63;
  if (lane == 0) red[wave] = m;
  __syncthreads();
  m = fmaxf(fmaxf(red[0], red[1]), fmaxf(red[2], red[3]));

  float s = 0.f;
#pragma unroll
  for (int e = 0; e < 16; ++e) { v[e] = __expf(v[e] - m); s += v[e]; }
#pragma unroll
  for (int off = 32; off; off >>= 1) s += __shfl_xor(s, off);
  if (lane == 0) red[4 + wave] = s;
  __syncthreads();
  s = red[4] + red[5] + red[6] + red[7];
  float inv = 1.0f / s;

#pragma unroll
  for (int j = 0; j < 2; ++j) {
#pragma unroll
    for (int e = 0; e < 8; ++e) h[j][e] = (f16)(v[j * 8 + e] * inv);
    reinterpret_cast<f16x8*>(rp)[tid + j * 256] = h[j];
  }
}

// ---------------------------------------------------------------- launch
extern "C" void kernel_launch(void* const* d_in, const int* in_sizes, int n_in,
                              void* d_out, int out_size, void* d_ws, size_t ws_size,
                              hipStream_t stream) {
  const float* hs   = (const float*)d_in[0];
  const float* mask = (const float*)d_in[1];
  const float* Wq   = (const float*)d_in[2];
  const float* bq   = (const float*)d_in[3];
  const float* Wk   = (const float*)d_in[4];
  const float* bk   = (const float*)d_in[5];
  const float* Wv   = (const float*)d_in[6];
  const float* bv   = (const float*)d_in[7];
  float* out = (float*)d_out;

  // workspace layout (~226 MB)
  f16* hs_h = (f16*)d_ws;                        // B*S*H
  f16* w_h  = hs_h + (size_t)B * S * H;          // 3*H*H concat
  f16* Qh   = w_h + (size_t)3 * H * H;           // B*S*H
  f16* Kh   = Qh + (size_t)B * S * H;            // B*S*H
  f16* Vt   = Kh + (size_t)B * S * H;            // B*H*S (transposed)
  f16* Sc   = Vt + (size_t)B * S * H;            // B*S*S f16

  const int castN = B * S * H / 4 + 3 * H * H / 4;
  cast_all<<<(castN + 255) / 256, 256, 0, stream>>>(hs, Wq, Wk, Wv, hs_h, w_h);

  dim3 blk(256);
  const float sscale = 0.088388347648318447f;  // 1/sqrt(HEAD_SIZE=128)

  // fused QKV: M=8192, N=6144, K=2048. grid (48,64), x fastest
  gemm_tn<0><<<dim3(48, 64), blk, 0, stream>>>(
      hs_h, w_h, Qh, Kh, Vt, bq, bk, bv, 1.f, H, H, H);

  // scores both batches: M=8192, N=4096, K=2048. grid (32,64)
  gemm_tn<2><<<dim3(32, 64), blk, 0, stream>>>(
      Qh, Kh, Sc, nullptr, nullptr, mask, nullptr, nullptr, sscale, H, H, H);

  softmax_f16<<<B * S, 256, 0, stream>>>(Sc);

  // PV both batches: M=8192, N=2048, K=4096. grid (16,64)
  gemm_tn<3><<<dim3(16, 64), blk, 0, stream>>>(
      Sc, Vt, out, nullptr, nullptr, nullptr, nullptr, nullptr, 1.f, S, S, S);
}